// Round 1
// baseline (779.409 us; speedup 1.0000x reference)
//
#include <hip/hip_runtime.h>

typedef short bf16x8 __attribute__((ext_vector_type(8)));
typedef float f32x4  __attribute__((ext_vector_type(4)));

#define T_TOK 16384
#define HD 768
#define ID 3072
#define NE 8

__device__ __forceinline__ unsigned short f2bf(float f) {
    unsigned int u = __float_as_uint(f);
    unsigned int r = (u + 0x7FFFu + ((u >> 16) & 1u)) >> 16;   // RNE
    return (unsigned short)r;
}

__device__ __forceinline__ void gload16(const void* g, void* l) {
    __builtin_amdgcn_global_load_lds(
        (const __attribute__((address_space(1))) void*)g,
        (__attribute__((address_space(3))) void*)l, 16, 0, 0);
}

// ---------------- x f32 -> bf16 ----------------
__global__ __launch_bounds__(256) void k_cvt_x(const float* __restrict__ x,
                                               unsigned short* __restrict__ xb) {
    int i = blockIdx.x * 256 + threadIdx.x;           // 4 floats each
    float4 v = ((const float4*)x)[i];
    ushort4 o;
    o.x = f2bf(v.x); o.y = f2bf(v.y); o.z = f2bf(v.z); o.w = f2bf(v.w);
    ((ushort4*)xb)[i] = o;
}

// ---------------- transpose + cvt: in [E][R][C] f32 -> out [E][C][R] bf16 ----
__global__ __launch_bounds__(256) void k_tp(const float* __restrict__ in,
                                            unsigned short* __restrict__ out,
                                            int R, int C) {
    __shared__ float t[64][65];
    const float* ine = in + (size_t)blockIdx.z * R * C;
    unsigned short* oute = out + (size_t)blockIdx.z * R * C;
    int c0 = blockIdx.x * 64, r0 = blockIdx.y * 64;
    int lc = threadIdx.x & 63, lr4 = threadIdx.x >> 6;
#pragma unroll
    for (int i = 0; i < 16; i++) {
        int r = i * 4 + lr4;
        t[r][lc] = ine[(size_t)(r0 + r) * C + c0 + lc];
    }
    __syncthreads();
#pragma unroll
    for (int i = 0; i < 16; i++) {
        int r = i * 4 + lr4;   // output row index within tile (= source col)
        oute[(size_t)(c0 + r) * R + r0 + lc] = f2bf(t[lc][r]);
    }
}

// ---------------- router: wave per token, f32 ----------------
__global__ __launch_bounds__(256) void k_router(const float* __restrict__ x,
                                                const float* __restrict__ rw,
                                                int* __restrict__ topE,
                                                float* __restrict__ topW) {
    __shared__ float lrw[NE * HD];
    for (int i = threadIdx.x; i < NE * HD; i += 256) lrw[i] = rw[i];
    __syncthreads();
    int lane = threadIdx.x & 63;
    int t = blockIdx.x * 4 + (threadIdx.x >> 6);
    const float* xr = x + (size_t)t * HD;
    float acc[NE] = {0, 0, 0, 0, 0, 0, 0, 0};
    for (int h = lane; h < HD; h += 64) {
        float xv = xr[h];
#pragma unroll
        for (int e = 0; e < NE; e++) acc[e] = fmaf(xv, lrw[e * HD + h], acc[e]);
    }
#pragma unroll
    for (int e = 0; e < NE; e++) {
        float v = acc[e];
#pragma unroll
        for (int o = 32; o > 0; o >>= 1) v += __shfl_xor(v, o, 64);
        acc[e] = v;
    }
    if (lane == 0) {
        int e1 = 0; float l1 = acc[0];
#pragma unroll
        for (int e = 1; e < NE; e++) if (acc[e] > l1) { l1 = acc[e]; e1 = e; }
        int e2 = -1; float l2 = -1e30f;
#pragma unroll
        for (int e = 0; e < NE; e++) if (e != e1 && acc[e] > l2) { l2 = acc[e]; e2 = e; }
        float ex = expf(l2 - l1);
        float w1 = 1.0f / (1.0f + ex);
        topE[2 * t] = e1; topE[2 * t + 1] = e2;
        topW[2 * t] = w1; topW[2 * t + 1] = ex * w1;
    }
}

// ---------------- scatter into per-expert lists ----------------
__global__ __launch_bounds__(256) void k_scatter(const int* __restrict__ topE,
                                                 const float* __restrict__ topW,
                                                 int* __restrict__ counts,
                                                 int* __restrict__ tokL,
                                                 float* __restrict__ gateL) {
    __shared__ int lc[NE], lbase[NE];
    if (threadIdx.x < NE) lc[threadIdx.x] = 0;
    __syncthreads();
    int t = blockIdx.x * 256 + threadIdx.x;
    int e1 = topE[2 * t], e2 = topE[2 * t + 1];
    int p1 = atomicAdd(&lc[e1], 1);
    int p2 = atomicAdd(&lc[e2], 1);
    __syncthreads();
    if (threadIdx.x < NE) lbase[threadIdx.x] = atomicAdd(&counts[threadIdx.x], lc[threadIdx.x]);
    __syncthreads();
    int q1 = lbase[e1] + p1, q2 = lbase[e2] + p2;
    tokL[e1 * T_TOK + q1] = t;  gateL[e1 * T_TOK + q1] = topW[2 * t];
    tokL[e2 * T_TOK + q2] = t;  gateL[e2 * T_TOK + q2] = topW[2 * t + 1];
}

// ---------------- fused MoE GEMM: 64 tokens x 1 expert per block ----------------
// LDS: xs [64][1536B] swizzled (96KB) | hs [64][128B] swizzled (8KB) | ring 6x8KB
__global__ __launch_bounds__(512, 2) void k_moe(
    const unsigned short* __restrict__ xb,
    const unsigned short* __restrict__ upt,   // [E][ID][HD] bf16
    const unsigned short* __restrict__ dnt,   // [E][HD][ID] bf16
    const int* __restrict__ counts,
    const int* __restrict__ tokL,
    const float* __restrict__ gateL,
    float* __restrict__ out) {
    __shared__ __align__(16) char lds[155648];
    char* xs = lds;
    char* hs = lds + 98304;
    char* ring = lds + 106496;

    const int e = blockIdx.x & 7;
    const int slot = blockIdx.x >> 3;
    const int cnt = counts[e];
    if (slot * 64 >= cnt) return;
    const int nrow = min(64, cnt - slot * 64);
    const int* tok = tokL + e * T_TOK + slot * 64;
    const float* gat = gateL + e * T_TOK + slot * 64;

    const int tid = threadIdx.x;
    const int lane = tid & 63;
    const int wid = tid >> 6;
    const int mi = wid >> 2, ni = wid & 3;

    const char* upe = (const char*)(upt + (size_t)e * ID * HD);  // row = i, 1536 B
    const char* dne = (const char*)(dnt + (size_t)e * HD * ID);  // row = h, 6144 B

    // ---- stage x tile (gather rows by token id), swizzled source
    {
        int off = tid * 16;
#pragma unroll
        for (int s = 0; s < 12; s++) {
            int o = off + s * 8192;
            int m = o / 1536;
            int cb = o - m * 1536;
            int tk = (m < nrow) ? tok[m] : tok[0];
            const char* src = (const char*)xb + (size_t)tk * 1536 + (size_t)(cb ^ ((m & 7) << 4));
            gload16(src, xs + s * 8192 + wid * 1024);
        }
    }
    asm volatile("s_waitcnt vmcnt(0)" ::: "memory");
    __builtin_amdgcn_s_barrier();
    asm volatile("" ::: "memory");

    auto issue = [&](int s) {
        char* dst = ring + (s % 6) * 8192 + wid * 1024;
        int ci = s / 24;
        int ph = s - ci * 24;
        int row = tid >> 3;
        int cb = (tid & 7) << 4;
        int scb = cb ^ ((row & 7) << 4);
        const char* src;
        if (ci >= 48) src = upe;  // dummy (keeps vmcnt arithmetic constant)
        else if (ph < 12) src = upe + (size_t)(ci * 64 + row) * 1536 + ph * 128 + scb;
        else              src = dne + (size_t)((ph - 12) * 64 + row) * 6144 + ci * 128 + scb;
        gload16(src, dst);
    };

    f32x4 acc[2][12];
#pragma unroll
    for (int a = 0; a < 2; a++)
#pragma unroll
        for (int b = 0; b < 12; b++) acc[a][b] = (f32x4){0.f, 0.f, 0.f, 0.f};

    issue(0); issue(1); issue(2); issue(3);

    f32x4 acch[2];
    bf16x8 ha[2][2];

    for (int ci = 0; ci < 48; ci++) {
        // -------- phase A: h[64x64] = X[64x768] @ up[768x64] --------
#pragma unroll
        for (int ks = 0; ks < 12; ks++) {
            issue(ci * 24 + ks + 4);
            asm volatile("s_waitcnt vmcnt(4)" ::: "memory");
            __builtin_amdgcn_s_barrier();
            asm volatile("" ::: "memory");
            char* buf = ring + (ks % 6) * 8192;
            if (ks == 0) { acch[0] = (f32x4){0.f,0.f,0.f,0.f}; acch[1] = (f32x4){0.f,0.f,0.f,0.f}; }
#pragma unroll
            for (int kr = 0; kr < 2; kr++) {
                int bn = ni * 16 + (lane & 15);
                int bo = ((kr * 32 + (lane >> 4) * 8) * 2) ^ ((bn & 7) << 4);
                bf16x8 bfrag = *(const bf16x8*)(buf + bn * 128 + bo);
#pragma unroll
                for (int mr = 0; mr < 2; mr++) {
                    int ar = mi * 32 + mr * 16 + (lane & 15);
                    int ao = ((ks * 64 + kr * 32 + (lane >> 4) * 8) * 2) ^ ((ar & 7) << 4);
                    bf16x8 afrag = *(const bf16x8*)(xs + ar * 1536 + ao);
                    acch[mr] = __builtin_amdgcn_mfma_f32_16x16x32_bf16(afrag, bfrag, acch[mr], 0, 0, 0);
                }
            }
            if (ks == 11) {  // gelu + write h tile (bf16, swizzled)
#pragma unroll
                for (int mr = 0; mr < 2; mr++) {
                    int col = ni * 16 + (lane & 15);
#pragma unroll
                    for (int r = 0; r < 4; r++) {
                        int m = mi * 32 + mr * 16 + (lane >> 4) * 4 + r;
                        float v = acch[mr][r];
                        float g = 0.5f * v * (1.0f + erff(v * 0.70710678118f));
                        *(unsigned short*)(hs + m * 128 + ((col * 2) ^ ((m & 7) << 4))) = f2bf(g);
                    }
                }
                asm volatile("s_waitcnt lgkmcnt(0)" ::: "memory");
            }
        }
        // -------- phase B: acc[64x768] += gelu(h) @ down[64x768] --------
#pragma unroll
        for (int j = 0; j < 12; j++) {
            issue(ci * 24 + 12 + j + 4);
            asm volatile("s_waitcnt vmcnt(4)" ::: "memory");
            __builtin_amdgcn_s_barrier();
            asm volatile("" ::: "memory");
            char* buf = ring + ((12 + j) % 6) * 8192;
            if (j == 0) {
#pragma unroll
                for (int mr = 0; mr < 2; mr++)
#pragma unroll
                    for (int kr = 0; kr < 2; kr++) {
                        int ar = mi * 32 + mr * 16 + (lane & 15);
                        int ao = ((kr * 32 + (lane >> 4) * 8) * 2) ^ ((ar & 7) << 4);
                        ha[mr][kr] = *(const bf16x8*)(hs + ar * 128 + ao);
                    }
            }
#pragma unroll
            for (int kr = 0; kr < 2; kr++) {
                int bn = ni * 16 + (lane & 15);
                int bo = ((kr * 32 + (lane >> 4) * 8) * 2) ^ ((bn & 7) << 4);
                bf16x8 bfrag = *(const bf16x8*)(buf + bn * 128 + bo);
#pragma unroll
                for (int mr = 0; mr < 2; mr++)
                    acc[mr][j] = __builtin_amdgcn_mfma_f32_16x16x32_bf16(ha[mr][kr], bfrag, acc[mr][j], 0, 0, 0);
            }
        }
    }

    // -------- epilogue: gate + atomicAdd into out --------
    int   t4[2][4];
    float g4[2][4];
#pragma unroll
    for (int mr = 0; mr < 2; mr++)
#pragma unroll
        for (int r = 0; r < 4; r++) {
            int m = mi * 32 + mr * 16 + (lane >> 4) * 4 + r;
            bool valid = m < nrow;
            t4[mr][r] = valid ? tok[m] : -1;
            g4[mr][r] = valid ? gat[m] : 0.f;
        }
#pragma unroll
    for (int mr = 0; mr < 2; mr++)
#pragma unroll
        for (int j = 0; j < 12; j++) {
            int colg = j * 64 + ni * 16 + (lane & 15);
#pragma unroll
            for (int r = 0; r < 4; r++) {
                if (t4[mr][r] >= 0)
                    atomicAdd(out + (size_t)t4[mr][r] * HD + colg, g4[mr][r] * acc[mr][j][r]);
            }
        }
}

extern "C" void kernel_launch(void* const* d_in, const int* in_sizes, int n_in,
                              void* d_out, int out_size, void* d_ws, size_t ws_size,
                              hipStream_t stream) {
    const float* x  = (const float*)d_in[0];
    const float* rw = (const float*)d_in[1];
    const float* uw = (const float*)d_in[2];
    const float* dw = (const float*)d_in[3];
    float* out = (float*)d_out;

    char* w = (char*)d_ws;
    unsigned short* xb  = (unsigned short*)w; w += (size_t)T_TOK * HD * 2;
    unsigned short* upt = (unsigned short*)w; w += (size_t)NE * ID * HD * 2;
    unsigned short* dnt = (unsigned short*)w; w += (size_t)NE * HD * ID * 2;
    int*   topE   = (int*)w;   w += (size_t)T_TOK * 2 * 4;
    float* topW   = (float*)w; w += (size_t)T_TOK * 2 * 4;
    int*   counts = (int*)w;   w += 256;
    int*   tokL   = (int*)w;   w += (size_t)NE * T_TOK * 4;
    float* gateL  = (float*)w; w += (size_t)NE * T_TOK * 4;

    hipMemsetAsync(d_out, 0, (size_t)T_TOK * HD * 4, stream);
    hipMemsetAsync(counts, 0, 256, stream);

    k_cvt_x<<<(T_TOK * HD) / (256 * 4), 256, 0, stream>>>(x, xb);
    k_tp<<<dim3(ID / 64, HD / 64, NE), 256, 0, stream>>>(uw, upt, HD, ID);   // -> [i][h]
    k_tp<<<dim3(HD / 64, ID / 64, NE), 256, 0, stream>>>(dw, dnt, ID, HD);   // -> [h][i]
    k_router<<<T_TOK / 4, 256, 0, stream>>>(x, rw, topE, topW);
    k_scatter<<<T_TOK / 256, 256, 0, stream>>>(topE, topW, counts, tokL, gateL);
    k_moe<<<2048, 512, 0, stream>>>(xb, upt, dnt, counts, tokL, gateL, out);
}

// Round 2
// 770.205 us; speedup vs baseline: 1.0120x; 1.0120x over previous
//
#include <hip/hip_runtime.h>

typedef short bf16x8 __attribute__((ext_vector_type(8)));
typedef float f32x4  __attribute__((ext_vector_type(4)));

#define T_TOK 16384
#define HD 768
#define ID 3072
#define NE 8
#define NT1MAX 136

__device__ __forceinline__ unsigned short f2bf(float f) {
    unsigned int u = __float_as_uint(f);
    unsigned int r = (u + 0x7FFFu + ((u >> 16) & 1u)) >> 16;   // RNE
    return (unsigned short)r;
}

__device__ __forceinline__ void gload16(const void* g, void* l) {
    __builtin_amdgcn_global_load_lds(
        (const __attribute__((address_space(1))) void*)g,
        (__attribute__((address_space(3))) void*)l, 16, 0, 0);
}

__device__ __forceinline__ float gelu_f(float x) {
    // exact-GELU via A&S 7.1.26 erf approx (|err| <= 1.5e-7, invisible at bf16)
    float z = fabsf(x) * 0.70710678118f;
    float t = 1.0f / fmaf(0.3275911f, z, 1.0f);
    float p = t * fmaf(t, fmaf(t, fmaf(t, fmaf(t, 1.061405429f, -1.453152027f),
                                       1.421413741f), -0.284496736f), 0.254829592f);
    float e = 1.0f - p * __expf(-z * z);
    float erfv = (x >= 0.f) ? e : -e;
    return 0.5f * x * (1.0f + erfv);
}

// ---------------- x f32 -> bf16 ----------------
__global__ __launch_bounds__(256) void k_cvt_x(const float* __restrict__ x,
                                               unsigned short* __restrict__ xb) {
    int i = blockIdx.x * 256 + threadIdx.x;
    float4 v = ((const float4*)x)[i];
    ushort4 o;
    o.x = f2bf(v.x); o.y = f2bf(v.y); o.z = f2bf(v.z); o.w = f2bf(v.w);
    ((ushort4*)xb)[i] = o;
}

// ---------------- transpose + cvt: in [E][R][C] f32 -> out [E][C][R] bf16 ----
__global__ __launch_bounds__(256) void k_tp(const float* __restrict__ in,
                                            unsigned short* __restrict__ out,
                                            int R, int C) {
    __shared__ float t[64][65];
    const float* ine = in + (size_t)blockIdx.z * R * C;
    unsigned short* oute = out + (size_t)blockIdx.z * R * C;
    int c0 = blockIdx.x * 64, r0 = blockIdx.y * 64;
    int lc = threadIdx.x & 63, lr4 = threadIdx.x >> 6;
#pragma unroll
    for (int i = 0; i < 16; i++) {
        int r = i * 4 + lr4;
        t[r][lc] = ine[(size_t)(r0 + r) * C + c0 + lc];
    }
    __syncthreads();
#pragma unroll
    for (int i = 0; i < 16; i++) {
        int r = i * 4 + lr4;
        oute[(size_t)(c0 + r) * R + r0 + lc] = f2bf(t[lc][r]);
    }
}

// ---------------- router: wave per token, f32 ----------------
__global__ __launch_bounds__(256) void k_router(const float* __restrict__ x,
                                                const float* __restrict__ rw,
                                                int* __restrict__ topE,
                                                float* __restrict__ topW) {
    __shared__ float lrw[NE * HD];
    for (int i = threadIdx.x; i < NE * HD; i += 256) lrw[i] = rw[i];
    __syncthreads();
    int lane = threadIdx.x & 63;
    int t = blockIdx.x * 4 + (threadIdx.x >> 6);
    const float* xr = x + (size_t)t * HD;
    float acc[NE] = {0, 0, 0, 0, 0, 0, 0, 0};
    for (int h = lane; h < HD; h += 64) {
        float xv = xr[h];
#pragma unroll
        for (int e = 0; e < NE; e++) acc[e] = fmaf(xv, lrw[e * HD + h], acc[e]);
    }
#pragma unroll
    for (int e = 0; e < NE; e++) {
        float v = acc[e];
#pragma unroll
        for (int o = 32; o > 0; o >>= 1) v += __shfl_xor(v, o, 64);
        acc[e] = v;
    }
    if (lane == 0) {
        int e1 = 0; float l1 = acc[0];
#pragma unroll
        for (int e = 1; e < NE; e++) if (acc[e] > l1) { l1 = acc[e]; e1 = e; }
        int e2 = -1; float l2 = -1e30f;
#pragma unroll
        for (int e = 0; e < NE; e++) if (e != e1 && acc[e] > l2) { l2 = acc[e]; e2 = e; }
        float ex = expf(l2 - l1);
        float w1 = 1.0f / (1.0f + ex);
        topE[2 * t] = e1; topE[2 * t + 1] = e2;
        topW[2 * t] = w1; topW[2 * t + 1] = ex * w1;
    }
}

// ---------------- scatter into per-expert lists ----------------
__global__ __launch_bounds__(256) void k_scatter(const int* __restrict__ topE,
                                                 const float* __restrict__ topW,
                                                 int* __restrict__ counts,
                                                 int* __restrict__ tokL,
                                                 float* __restrict__ gateL) {
    __shared__ int lc[NE], lbase[NE];
    if (threadIdx.x < NE) lc[threadIdx.x] = 0;
    __syncthreads();
    int t = blockIdx.x * 256 + threadIdx.x;
    int e1 = topE[2 * t], e2 = topE[2 * t + 1];
    int p1 = atomicAdd(&lc[e1], 1);
    int p2 = atomicAdd(&lc[e2], 1);
    __syncthreads();
    if (threadIdx.x < NE) lbase[threadIdx.x] = atomicAdd(&counts[threadIdx.x], lc[threadIdx.x]);
    __syncthreads();
    int q1 = lbase[e1] + p1, q2 = lbase[e2] + p2;
    tokL[e1 * T_TOK + q1] = t;  gateL[e1 * T_TOK + q1] = topW[2 * t];
    tokL[e2 * T_TOK + q2] = t;  gateL[e2 * T_TOK + q2] = topW[2 * t + 1];
}

// ---------------- tile descriptor build (tiny) ----------------
__global__ void k_desc(const int* __restrict__ counts, int* __restrict__ tileE,
                       int* __restrict__ tileM0, int* __restrict__ tileHB) {
    if (threadIdx.x == 0 && blockIdx.x == 0) {
        int off = 0, tl = 0;
        for (int e = 0; e < NE; e++) {
            int c = counts[e];
            int nt = (c + 255) >> 8;
            for (int t = 0; t < nt; t++) {
                tileE[tl] = e; tileM0[tl] = t << 8; tileHB[tl] = off + (t << 8); tl++;
            }
            off += c;
        }
        for (; tl < NT1MAX; tl++) { tileE[tl] = -1; tileM0[tl] = 0; tileHB[tl] = 0; }
    }
}

// ============ grouped GEMM1: h[rows x 3072] = gelu( Xg[rows x 768] @ up^T ) ============
// 256x256 tile, BK=32, 4-slot LDS ring (128KB), depth-3 prefetch, vmcnt(8).
// LDS per slot: A [16 sub][4 kgrp][16 row]x16B (16KB) + B same (16KB) -> frag ds_reads
// are contiguous-1KB permutations (conflict-free).
__global__ __launch_bounds__(512, 2) void k_gemm1(
    const unsigned short* __restrict__ xb,
    const unsigned short* __restrict__ upt,     // [E][I][H] bf16
    const int* __restrict__ tokL,
    const int* __restrict__ counts,
    const int* __restrict__ tileE,
    const int* __restrict__ tileM0,
    const int* __restrict__ tileHB,
    unsigned short* __restrict__ h) {
    __shared__ __align__(16) char lds[4][32768];
    constexpr int NK = HD / 32;                 // 24
    constexpr int NWG = NT1MAX * 12;            // 1632, %8==0
    int bid = blockIdx.x;
    int L = (bid & 7) * (NWG >> 3) + (bid >> 3);    // XCD-chunked
    int mt = L / 12, nt = L - mt * 12;
    int e = tileE[mt];
    if (e < 0) return;
    int m0 = tileM0[mt];
    int hb = tileHB[mt];
    int nrow = min(256, counts[e] - m0);
    const int* tok = tokL + e * T_TOK + m0;
    int n0 = nt * 256;

    const int tid = threadIdx.x, lane = tid & 63, wid = tid >> 6;
    const int wm = wid >> 2, wn = wid & 3;
    const int g = lane >> 4, r = lane & 15;

    int ar0 = wid * 16 + r;
    int ar1 = 128 + wid * 16 + r;
    const char* a0 = (const char*)(xb + (size_t)tok[ar0 < nrow ? ar0 : 0] * HD);
    const char* a1 = (const char*)(xb + (size_t)tok[ar1 < nrow ? ar1 : 0] * HD);
    const char* bsl = (const char*)(upt + (size_t)e * ID * HD);
    const char* b0 = bsl + (size_t)(n0 + wid * 16 + r) * (HD * 2);
    const char* b1 = bsl + (size_t)(n0 + 128 + wid * 16 + r) * (HD * 2);
    const int dstoff = wid * 1024 + lane * 16;
    const int koff = g * 16;

    auto issue = [&](int step, int slot) {
        char* base = &lds[slot][0];
        int kb = step * 64 + koff;
        gload16(a0 + kb, base + dstoff);
        gload16(a1 + kb, base + 8192 + dstoff);
        gload16(b0 + kb, base + 16384 + dstoff);
        gload16(b1 + kb, base + 24576 + dstoff);
    };

    f32x4 acc[8][4];
#pragma unroll
    for (int m = 0; m < 8; m++)
#pragma unroll
        for (int n = 0; n < 4; n++) acc[m][n] = (f32x4){0.f, 0.f, 0.f, 0.f};

    issue(0, 0); issue(1, 1); issue(2, 2);
    asm volatile("s_waitcnt vmcnt(8)" ::: "memory");
    __builtin_amdgcn_s_barrier();
    asm volatile("" ::: "memory");

    const int aoff = wm * 8192 + g * 256 + r * 16;
    const int boff = 16384 + wn * 4096 + g * 256 + r * 16;

    for (int k = 0; k < NK; k++) {
        char* base = &lds[k & 3][0];
        bf16x8 a[4], b[4];
#pragma unroll
        for (int n = 0; n < 4; n++) b[n] = *(const bf16x8*)(base + boff + n * 1024);
#pragma unroll
        for (int m = 0; m < 4; m++) a[m] = *(const bf16x8*)(base + aoff + m * 1024);
        issue(min(k + 3, NK - 1), (k + 3) & 3);
        __builtin_amdgcn_s_setprio(1);
#pragma unroll
        for (int m = 0; m < 4; m++)
#pragma unroll
            for (int n = 0; n < 4; n++)
                acc[m][n] = __builtin_amdgcn_mfma_f32_16x16x32_bf16(a[m], b[n], acc[m][n], 0, 0, 0);
        __builtin_amdgcn_s_setprio(0);
#pragma unroll
        for (int m = 0; m < 4; m++) a[m] = *(const bf16x8*)(base + aoff + (4 + m) * 1024);
        __builtin_amdgcn_s_setprio(1);
#pragma unroll
        for (int m = 0; m < 4; m++)
#pragma unroll
            for (int n = 0; n < 4; n++)
                acc[4 + m][n] = __builtin_amdgcn_mfma_f32_16x16x32_bf16(a[m], b[n], acc[4 + m][n], 0, 0, 0);
        __builtin_amdgcn_s_setprio(0);
        asm volatile("s_waitcnt vmcnt(8)" ::: "memory");
        __builtin_amdgcn_s_barrier();
        asm volatile("" ::: "memory");
    }
    asm volatile("s_waitcnt vmcnt(0)" ::: "memory");

#pragma unroll
    for (int m = 0; m < 8; m++)
#pragma unroll
        for (int j = 0; j < 4; j++) {
            int rl = wm * 128 + m * 16 + g * 4 + j;
            if (rl < nrow) {
                unsigned short* hr = h + (size_t)(hb + rl) * ID + n0 + wn * 64 + r;
#pragma unroll
                for (int n = 0; n < 4; n++) hr[n * 16] = f2bf(gelu_f(acc[m][n][j]));
            }
        }
}

// ============ grouped GEMM2: out[tok] += gate * ( h[rows x 3072] @ down^T ) ============
__global__ __launch_bounds__(512, 2) void k_gemm2(
    const unsigned short* __restrict__ h,
    const unsigned short* __restrict__ dnt,     // [E][H][I] bf16
    const int* __restrict__ tokL,
    const float* __restrict__ gateL,
    const int* __restrict__ counts,
    const int* __restrict__ tileE,
    const int* __restrict__ tileM0,
    const int* __restrict__ tileHB,
    float* __restrict__ out) {
    __shared__ __align__(16) char lds[4][32768];
    constexpr int NK = ID / 32;                 // 96
    constexpr int NWG = NT1MAX * 3;             // 408, %8==0
    int bid = blockIdx.x;
    int L = (bid & 7) * (NWG >> 3) + (bid >> 3);
    int mt = L / 3, nt = L - mt * 3;
    int e = tileE[mt];
    if (e < 0) return;
    int m0 = tileM0[mt];
    int hb = tileHB[mt];
    int nrow = min(256, counts[e] - m0);
    const int* tok = tokL + e * T_TOK + m0;
    const float* gat = gateL + e * T_TOK + m0;
    int n0 = nt * 256;

    const int tid = threadIdx.x, lane = tid & 63, wid = tid >> 6;
    const int wm = wid >> 2, wn = wid & 3;
    const int g = lane >> 4, r = lane & 15;

    int ar0 = wid * 16 + r;
    int ar1 = 128 + wid * 16 + r;
    const char* a0 = (const char*)(h + (size_t)(hb + ar0) * ID);   // pad rows: row-isolated garbage
    const char* a1 = (const char*)(h + (size_t)(hb + ar1) * ID);
    const char* bsl = (const char*)(dnt + (size_t)e * ID * HD);
    const char* b0 = bsl + (size_t)(n0 + wid * 16 + r) * (ID * 2);
    const char* b1 = bsl + (size_t)(n0 + 128 + wid * 16 + r) * (ID * 2);
    const int dstoff = wid * 1024 + lane * 16;
    const int koff = g * 16;

    auto issue = [&](int step, int slot) {
        char* base = &lds[slot][0];
        int kb = step * 64 + koff;
        gload16(a0 + kb, base + dstoff);
        gload16(a1 + kb, base + 8192 + dstoff);
        gload16(b0 + kb, base + 16384 + dstoff);
        gload16(b1 + kb, base + 24576 + dstoff);
    };

    f32x4 acc[8][4];
#pragma unroll
    for (int m = 0; m < 8; m++)
#pragma unroll
        for (int n = 0; n < 4; n++) acc[m][n] = (f32x4){0.f, 0.f, 0.f, 0.f};

    issue(0, 0); issue(1, 1); issue(2, 2);
    asm volatile("s_waitcnt vmcnt(8)" ::: "memory");
    __builtin_amdgcn_s_barrier();
    asm volatile("" ::: "memory");

    const int aoff = wm * 8192 + g * 256 + r * 16;
    const int boff = 16384 + wn * 4096 + g * 256 + r * 16;

    for (int k = 0; k < NK; k++) {
        char* base = &lds[k & 3][0];
        bf16x8 a[4], b[4];
#pragma unroll
        for (int n = 0; n < 4; n++) b[n] = *(const bf16x8*)(base + boff + n * 1024);
#pragma unroll
        for (int m = 0; m < 4; m++) a[m] = *(const bf16x8*)(base + aoff + m * 1024);
        issue(min(k + 3, NK - 1), (k + 3) & 3);
        __builtin_amdgcn_s_setprio(1);
#pragma unroll
        for (int m = 0; m < 4; m++)
#pragma unroll
            for (int n = 0; n < 4; n++)
                acc[m][n] = __builtin_amdgcn_mfma_f32_16x16x32_bf16(a[m], b[n], acc[m][n], 0, 0, 0);
        __builtin_amdgcn_s_setprio(0);
#pragma unroll
        for (int m = 0; m < 4; m++) a[m] = *(const bf16x8*)(base + aoff + (4 + m) * 1024);
        __builtin_amdgcn_s_setprio(1);
#pragma unroll
        for (int m = 0; m < 4; m++)
#pragma unroll
            for (int n = 0; n < 4; n++)
                acc[4 + m][n] = __builtin_amdgcn_mfma_f32_16x16x32_bf16(a[m], b[n], acc[4 + m][n], 0, 0, 0);
        __builtin_amdgcn_s_setprio(0);
        asm volatile("s_waitcnt vmcnt(8)" ::: "memory");
        __builtin_amdgcn_s_barrier();
        asm volatile("" ::: "memory");
    }
    asm volatile("s_waitcnt vmcnt(0)" ::: "memory");

#pragma unroll
    for (int m = 0; m < 8; m++)
#pragma unroll
        for (int j = 0; j < 4; j++) {
            int rl = wm * 128 + m * 16 + g * 4 + j;
            if (rl < nrow) {
                int t = tok[rl];
                float gv = gat[rl];
                float* orow = out + (size_t)t * HD + n0 + wn * 64 + r;
#pragma unroll
                for (int n = 0; n < 4; n++)
                    atomicAdd(orow + n * 16, gv * acc[m][n][j]);
            }
        }
}

// ---------------- round-1 fused kernel (ws_size fallback) ----------------
__global__ __launch_bounds__(512, 2) void k_moe(
    const unsigned short* __restrict__ xb,
    const unsigned short* __restrict__ upt,
    const unsigned short* __restrict__ dnt,
    const int* __restrict__ counts,
    const int* __restrict__ tokL,
    const float* __restrict__ gateL,
    float* __restrict__ out) {
    __shared__ __align__(16) char lds[155648];
    char* xs = lds;
    char* hs = lds + 98304;
    char* ring = lds + 106496;

    const int e = blockIdx.x & 7;
    const int slot = blockIdx.x >> 3;
    const int cnt = counts[e];
    if (slot * 64 >= cnt) return;
    const int nrow = min(64, cnt - slot * 64);
    const int* tok = tokL + e * T_TOK + slot * 64;
    const float* gat = gateL + e * T_TOK + slot * 64;

    const int tid = threadIdx.x;
    const int lane = tid & 63;
    const int wid = tid >> 6;
    const int mi = wid >> 2, ni = wid & 3;

    const char* upe = (const char*)(upt + (size_t)e * ID * HD);
    const char* dne = (const char*)(dnt + (size_t)e * HD * ID);

    {
        int off = tid * 16;
#pragma unroll
        for (int s = 0; s < 12; s++) {
            int o = off + s * 8192;
            int m = o / 1536;
            int cb = o - m * 1536;
            int tk = (m < nrow) ? tok[m] : tok[0];
            const char* src = (const char*)xb + (size_t)tk * 1536 + (size_t)(cb ^ ((m & 7) << 4));
            gload16(src, xs + s * 8192 + wid * 1024);
        }
    }
    asm volatile("s_waitcnt vmcnt(0)" ::: "memory");
    __builtin_amdgcn_s_barrier();
    asm volatile("" ::: "memory");

    auto issue = [&](int s) {
        char* dst = ring + (s % 6) * 8192 + wid * 1024;
        int ci = s / 24;
        int ph = s - ci * 24;
        int row = tid >> 3;
        int cb = (tid & 7) << 4;
        int scb = cb ^ ((row & 7) << 4);
        const char* src;
        if (ci >= 48) src = upe;
        else if (ph < 12) src = upe + (size_t)(ci * 64 + row) * 1536 + ph * 128 + scb;
        else              src = dne + (size_t)((ph - 12) * 64 + row) * 6144 + ci * 128 + scb;
        gload16(src, dst);
    };

    f32x4 acc[2][12];
#pragma unroll
    for (int a = 0; a < 2; a++)
#pragma unroll
        for (int b = 0; b < 12; b++) acc[a][b] = (f32x4){0.f, 0.f, 0.f, 0.f};

    issue(0); issue(1); issue(2); issue(3);

    f32x4 acch[2];
    bf16x8 ha[2][2];

    for (int ci = 0; ci < 48; ci++) {
#pragma unroll
        for (int ks = 0; ks < 12; ks++) {
            issue(ci * 24 + ks + 4);
            asm volatile("s_waitcnt vmcnt(4)" ::: "memory");
            __builtin_amdgcn_s_barrier();
            asm volatile("" ::: "memory");
            char* buf = ring + (ks % 6) * 8192;
            if (ks == 0) { acch[0] = (f32x4){0.f,0.f,0.f,0.f}; acch[1] = (f32x4){0.f,0.f,0.f,0.f}; }
#pragma unroll
            for (int kr = 0; kr < 2; kr++) {
                int bn = ni * 16 + (lane & 15);
                int bo = ((kr * 32 + (lane >> 4) * 8) * 2) ^ ((bn & 7) << 4);
                bf16x8 bfrag = *(const bf16x8*)(buf + bn * 128 + bo);
#pragma unroll
                for (int mr = 0; mr < 2; mr++) {
                    int ar = mi * 32 + mr * 16 + (lane & 15);
                    int ao = ((ks * 64 + kr * 32 + (lane >> 4) * 8) * 2) ^ ((ar & 7) << 4);
                    bf16x8 afrag = *(const bf16x8*)(xs + ar * 1536 + ao);
                    acch[mr] = __builtin_amdgcn_mfma_f32_16x16x32_bf16(afrag, bfrag, acch[mr], 0, 0, 0);
                }
            }
            if (ks == 11) {
#pragma unroll
                for (int mr = 0; mr < 2; mr++) {
                    int col = ni * 16 + (lane & 15);
#pragma unroll
                    for (int r = 0; r < 4; r++) {
                        int m = mi * 32 + mr * 16 + (lane >> 4) * 4 + r;
                        float v = acch[mr][r];
                        *(unsigned short*)(hs + m * 128 + ((col * 2) ^ ((m & 7) << 4))) = f2bf(gelu_f(v));
                    }
                }
                asm volatile("s_waitcnt lgkmcnt(0)" ::: "memory");
            }
        }
#pragma unroll
        for (int j = 0; j < 12; j++) {
            issue(ci * 24 + 12 + j + 4);
            asm volatile("s_waitcnt vmcnt(4)" ::: "memory");
            __builtin_amdgcn_s_barrier();
            asm volatile("" ::: "memory");
            char* buf = ring + ((12 + j) % 6) * 8192;
            if (j == 0) {
#pragma unroll
                for (int mr = 0; mr < 2; mr++)
#pragma unroll
                    for (int kr = 0; kr < 2; kr++) {
                        int ar = mi * 32 + mr * 16 + (lane & 15);
                        int ao = ((kr * 32 + (lane >> 4) * 8) * 2) ^ ((ar & 7) << 4);
                        ha[mr][kr] = *(const bf16x8*)(hs + ar * 128 + ao);
                    }
            }
#pragma unroll
            for (int kr = 0; kr < 2; kr++) {
                int bn = ni * 16 + (lane & 15);
                int bo = ((kr * 32 + (lane >> 4) * 8) * 2) ^ ((bn & 7) << 4);
                bf16x8 bfrag = *(const bf16x8*)(buf + bn * 128 + bo);
#pragma unroll
                for (int mr = 0; mr < 2; mr++)
                    acc[mr][j] = __builtin_amdgcn_mfma_f32_16x16x32_bf16(ha[mr][kr], bfrag, acc[mr][j], 0, 0, 0);
            }
        }
    }

    int   t4[2][4];
    float g4[2][4];
#pragma unroll
    for (int mr = 0; mr < 2; mr++)
#pragma unroll
        for (int r = 0; r < 4; r++) {
            int m = mi * 32 + mr * 16 + (lane >> 4) * 4 + r;
            bool valid = m < nrow;
            t4[mr][r] = valid ? tok[m] : -1;
            g4[mr][r] = valid ? gat[m] : 0.f;
        }
#pragma unroll
    for (int mr = 0; mr < 2; mr++)
#pragma unroll
        for (int j = 0; j < 12; j++) {
            int colg = j * 64 + ni * 16 + (lane & 15);
#pragma unroll
            for (int r = 0; r < 4; r++) {
                if (t4[mr][r] >= 0)
                    atomicAdd(out + (size_t)t4[mr][r] * HD + colg, g4[mr][r] * acc[mr][j][r]);
            }
        }
}

extern "C" void kernel_launch(void* const* d_in, const int* in_sizes, int n_in,
                              void* d_out, int out_size, void* d_ws, size_t ws_size,
                              hipStream_t stream) {
    const float* x  = (const float*)d_in[0];
    const float* rw = (const float*)d_in[1];
    const float* uw = (const float*)d_in[2];
    const float* dw = (const float*)d_in[3];
    float* out = (float*)d_out;

    size_t off = 0;
    char* base = (char*)d_ws;
    auto alloc = [&](size_t bytes) -> char* {
        char* p = base + off;
        off += (bytes + 1023) & ~(size_t)1023;
        return p;
    };
    unsigned short* xb   = (unsigned short*)alloc((size_t)T_TOK * HD * 2);
    unsigned short* upt  = (unsigned short*)alloc((size_t)NE * ID * HD * 2);
    unsigned short* dnt  = (unsigned short*)alloc((size_t)NE * HD * ID * 2);
    int*   topE   = (int*)alloc((size_t)T_TOK * 2 * 4);
    float* topW   = (float*)alloc((size_t)T_TOK * 2 * 4);
    int*   counts = (int*)alloc(256);
    int*   tileE  = (int*)alloc(NT1MAX * 4);
    int*   tileM0 = (int*)alloc(NT1MAX * 4);
    int*   tileHB = (int*)alloc(NT1MAX * 4);
    int*   tokL   = (int*)alloc((size_t)NE * T_TOK * 4);
    float* gateL  = (float*)alloc((size_t)NE * T_TOK * 4);
    unsigned short* h = (unsigned short*)alloc((size_t)(T_TOK * 2 + 256) * ID * 2);
    size_t need = off;

    hipMemsetAsync(d_out, 0, (size_t)T_TOK * HD * 4, stream);
    hipMemsetAsync(counts, 0, 256, stream);

    k_cvt_x<<<(T_TOK * HD) / (256 * 4), 256, 0, stream>>>(x, xb);
    k_tp<<<dim3(ID / 64, HD / 64, NE), 256, 0, stream>>>(uw, upt, HD, ID);   // -> [i][h]
    k_tp<<<dim3(HD / 64, ID / 64, NE), 256, 0, stream>>>(dw, dnt, ID, HD);   // -> [h][i]
    k_router<<<T_TOK / 4, 256, 0, stream>>>(x, rw, topE, topW);
    k_scatter<<<T_TOK / 256, 256, 0, stream>>>(topE, topW, counts, tokL, gateL);

    if (ws_size >= need) {
        k_desc<<<1, 64, 0, stream>>>(counts, tileE, tileM0, tileHB);
        k_gemm1<<<NT1MAX * 12, 512, 0, stream>>>(xb, upt, tokL, counts, tileE, tileM0, tileHB, h);
        k_gemm2<<<NT1MAX * 3, 512, 0, stream>>>(h, dnt, tokL, gateL, counts, tileE, tileM0, tileHB, out);
    } else {
        k_moe<<<2048, 512, 0, stream>>>(xb, upt, dnt, counts, tokL, gateL, out);
    }
}